// Round 10
// baseline (236.780 us; speedup 1.0000x reference)
//
#include <hip/hip_runtime.h>
#include <hip/hip_bf16.h>
#include <hip/hip_cooperative_groups.h>

namespace cg = cooperative_groups;

// SMPL collapsed-form. R19: single cooperative mega-kernel (256 blocks x 512 thr,
// 64KB LDS, 1 block/CU co-resident) with two grid.sync()s replacing the two
// kernel boundaries of R18. Phase0 = k0 (928 virtual 256-thr units), Phase1 = k1
// (blocks 0..167), Phase2 = k2 (640 virtual blocks). Kernel bodies unchanged
// from R18; only the dispatch structure is fused to kill launch gaps (~15us of
// the 35us controllable budget; ~90us is harness poison-fill, already rooflined).
// B=1024, V=6890, NB=10, NJ=24, NP=207, NK=19.
constexpr int Vn   = 6890;
constexpr int VC3  = 20670;   // V*3
constexpr int NKB  = 216;     // K blocks of 32 (K padded to 6912)
constexpr int QT   = 224;     // q rows: [ones, v_template, 10 shapedirs, 207 posedirs]
constexpr int NMG  = 14;      // QT/16 m-frag groups per c-plane
constexpr int NCOL = 480;     // 456 (k,j) cols + 24 Jreg cols
constexpr int MC   = 1368;    // 456*3
constexpr int KCH  = 27;      // k-blocks per wave in k1 (216/8)

using bf16x8  = __attribute__((ext_vector_type(8))) short;
using floatx4 = __attribute__((ext_vector_type(4))) float;

__device__ __forceinline__ unsigned short f2bf(float f) {
    unsigned int u = __float_as_uint(f);
    unsigned int r = (u + 0x7FFFu + ((u >> 16) & 1u)) >> 16;
    return (unsigned short)r;
}

__global__ __launch_bounds__(512) void mega(
    const float* __restrict__ vt, const float* __restrict__ sdirs,
    const float* __restrict__ pdirs, const float* __restrict__ Jreg,
    const float* __restrict__ jreg, const float* __restrict__ wts,
    const float* __restrict__ beta, const float* __restrict__ theta,
    const float* __restrict__ trans,
    unsigned short* __restrict__ Af, unsigned short* __restrict__ Bf,
    unsigned short* __restrict__ Wb3, unsigned short* __restrict__ xbf,
    float* __restrict__ Jacc, float* __restrict__ w1g,
    float* __restrict__ Rsg, float* __restrict__ out)
{
    __shared__ __attribute__((aligned(16))) float smem[16384];   // 64 KB
    cg::grid_group grid = cg::this_grid();
    const int bid = blockIdx.x;       // 0..255
    const int t   = threadIdx.x;      // 0..511

    // ================= phase 0: build Af/Bf frags + Rsg/xbf ==================
    // 928 virtual units of 256 threads; 2 units per block, wave-aligned.
    {
        const int ul = t >> 8, tl = t & 255;
        float* sm = smem + ul * 6160;                 // 16*385 floats per unit
        for (int u = bid * 2 + ul; u < 928; u += 512) {
            if (u < 756) {                            // ---- part A
                int mg = u / 54, ub = u % 54;
                int fbase = ub * 384;
                for (int i = tl; i < 16 * 384; i += 256) {
                    int qr = i / 384, off = i % 384;
                    int q = mg * 16 + qr;
                    int gidx = fbase + off;
                    float v = 0.f;
                    if (q == 0) v = (gidx < VC3) ? 1.f : 0.f;
                    else {
                        const float* src = nullptr;
                        if (q == 1) src = vt;
                        else if (q < 12)  src = sdirs + (size_t)(q - 2) * VC3;
                        else if (q < 219) src = pdirs + (size_t)(q - 12) * VC3;
                        if (src && gidx < VC3) v = src[gidx];
                    }
                    sm[qr * 385 + off] = v;
                }
                __syncthreads();
                int ql = tl & 15, uul = tl >> 4;
                int uu = ub * 16 + uul;
                int kb = uu >> 2, quad = uu & 3;
                size_t foff = (size_t)(ql + quad * 16) * 8;
                const float* lrow = sm + ql * 385 + uul * 24;
                #pragma unroll
                for (int c = 0; c < 3; ++c) {
                    bf16x8 o;
                    #pragma unroll
                    for (int j = 0; j < 8; ++j) o[j] = (short)f2bf(lrow[3 * j + c]);
                    *(bf16x8*)(Af + ((size_t)(c * NMG + mg) * NKB + kb) * 512 + foff) = o;
                }
            } else if (u < 864) {                     // ---- part B
                int bx = u - 756;
                int v0 = bx * 64;
                float* js  = sm;                      // 64*19
                float* wsh = sm + 1216;               // 64*24
                float* Jsh = sm + 2752;               // 64*24
                for (int i = tl; i < 64 * 19; i += 256)
                    js[i] = (v0 * 19 + i < Vn * 19) ? jreg[v0 * 19 + i] : 0.f;
                for (int i = tl; i < 64 * 24; i += 256) {
                    wsh[i] = (v0 * 24 + i < Vn * 24) ? wts[v0 * 24 + i] : 0.f;
                    Jsh[i] = (v0 * 24 + i < Vn * 24) ? Jreg[v0 * 24 + i] : 0.f;
                }
                __syncthreads();
                for (int s = tl; s < 4096; s += 256) {
                    int clow = s & 15, w = s >> 4;
                    int vg = w & 7, chigh = w >> 3;
                    int col = chigh * 16 + clow;
                    int kb = (v0 >> 5) + (vg >> 2);
                    bf16x8 o;
                    #pragma unroll
                    for (int j = 0; j < 8; ++j) {
                        int vl = vg * 8 + j;
                        float val = 0.f;
                        if (col < 456)      val = js[vl * 19 + col / 24] * wsh[vl * 24 + col % 24];
                        else if (col < 480) val = Jsh[vl * 24 + (col - 456)];
                        o[j] = (short)f2bf(val);
                    }
                    *(bf16x8*)(Bf + ((size_t)chigh * NKB + kb) * 512
                                  + (size_t)(clow + (vg & 3) * 16) * 8) = o;
                }
            } else {                                  // ---- part C
                int bx = u - 864;
                float (*Rc)[24][9] = (float(*)[24][9])sm;
                int b0 = bx * 16;
                for (int i = tl; i < 384; i += 256) { // rodrigues
                    int bl = i / 24, j = i % 24;
                    float t0 = theta[(size_t)(b0 + bl) * 72 + j * 3 + 0];
                    float t1 = theta[(size_t)(b0 + bl) * 72 + j * 3 + 1];
                    float t2 = theta[(size_t)(b0 + bl) * 72 + j * 3 + 2];
                    float e0 = t0 + 1e-8f, e1 = t1 + 1e-8f, e2 = t2 + 1e-8f;
                    float angle = sqrtf(e0 * e0 + e1 * e1 + e2 * e2);
                    float half = 0.5f * angle;
                    float sh = sinf(half), ch = cosf(half);
                    float s = sh / angle;
                    float qx = t0 * s, qy = t1 * s, qz = t2 * s;
                    float qn = sqrtf(ch * ch + qx * qx + qy * qy + qz * qz);
                    float w = ch / qn, x = qx / qn, y = qy / qn, z = qz / qn;
                    float r0 = 1.f - 2.f * (y * y + z * z);
                    float r1 = 2.f * (x * y - w * z);
                    float r2 = 2.f * (x * z + w * y);
                    float r3 = 2.f * (x * y + w * z);
                    float r4 = 1.f - 2.f * (x * x + z * z);
                    float r5 = 2.f * (y * z - w * x);
                    float r6 = 2.f * (x * z - w * y);
                    float r7 = 2.f * (y * z + w * x);
                    float r8 = 1.f - 2.f * (x * x + y * y);
                    Rc[bl][j][0] = r0; Rc[bl][j][1] = r1; Rc[bl][j][2] = r2;
                    Rc[bl][j][3] = r3; Rc[bl][j][4] = r4; Rc[bl][j][5] = r5;
                    Rc[bl][j][6] = r6; Rc[bl][j][7] = r7; Rc[bl][j][8] = r8;
                    float* rg = Rsg + (size_t)(b0 + bl) * 216 + j * 9;
                    rg[0] = r0; rg[1] = r1; rg[2] = r2;
                    rg[3] = r3; rg[4] = r4; rg[5] = r5;
                    rg[6] = r6; rg[7] = r7; rg[8] = r8;
                }
                __syncthreads();
                for (int i = tl; i < 16 * QT; i += 256) {  // x frags
                    int q = i >> 4, bl = i & 15;
                    int b = b0 + bl;
                    float xv = 0.f;
                    if (q == 1) xv = 1.f;
                    else if (q >= 2 && q < 12) xv = beta[(size_t)b * 10 + (q - 2)];
                    else if (q >= 12 && q < 219) {
                        int p = q - 12;
                        int jj = 1 + p / 9, e = p % 9;
                        float rr = Rc[bl][jj][e];
                        if (e == 0 || e == 4 || e == 8) rr -= 1.f;
                        xv = rr;
                    }
                    xbf[((size_t)(b >> 4) * 7 + (q >> 5)) * 512
                        + (size_t)((b & 15) + ((q >> 3) & 3) * 16) * 8 + (q & 7)] = f2bf(xv);
                }
            }
            __syncthreads();                          // protect sm reuse next round
        }
    }
    grid.sync();
    // ================= phase 1: W-GEMM reduce (blocks 0..167) ================
    if (bid < 168) {
        float* red = smem;                            // 8*2048 floats
        const int tid = t;
        int wv = tid >> 6, l = tid & 63;
        int r = bid;
        int c = r / 56; r %= 56;
        int mt = r >> 3, nt = r & 7;
        int kb0 = wv * KCH;

        const unsigned short* ap = Af + ((size_t)(c * NMG + mt * 2) * NKB + kb0) * 512 + l * 8;
        const unsigned short* bp = Bf + ((size_t)(nt * 4) * NKB + kb0) * 512 + l * 8;

        floatx4 acc[2][4];
        #pragma unroll
        for (int mi = 0; mi < 2; ++mi)
            #pragma unroll
            for (int ni = 0; ni < 4; ++ni) acc[mi][ni] = floatx4{0.f, 0.f, 0.f, 0.f};

        bf16x8 a[3][2], b[3][4];
        // prologue loads
        a[0][0] = *(const bf16x8*)(ap + (size_t)(0 * NKB + 0) * 512);
        a[0][1] = *(const bf16x8*)(ap + (size_t)(1 * NKB + 0) * 512);
        b[0][0] = *(const bf16x8*)(bp + (size_t)(0 * NKB + 0) * 512);
        b[0][1] = *(const bf16x8*)(bp + (size_t)(1 * NKB + 0) * 512);
        b[0][2] = *(const bf16x8*)(bp + (size_t)(2 * NKB + 0) * 512);
        b[0][3] = *(const bf16x8*)(bp + (size_t)(3 * NKB + 0) * 512);
        a[1][0] = *(const bf16x8*)(ap + (size_t)(0 * NKB + 1) * 512);
        a[1][1] = *(const bf16x8*)(ap + (size_t)(1 * NKB + 1) * 512);
        b[1][0] = *(const bf16x8*)(bp + (size_t)(0 * NKB + 1) * 512);
        b[1][1] = *(const bf16x8*)(bp + (size_t)(1 * NKB + 1) * 512);
        b[1][2] = *(const bf16x8*)(bp + (size_t)(2 * NKB + 1) * 512);
        b[1][3] = *(const bf16x8*)(bp + (size_t)(3 * NKB + 1) * 512);
        #pragma unroll
        for (int i = 0; i < KCH; ++i) {
            if (i + 2 < KCH) {
                int nx = (i + 2) % 3;
                a[nx][0] = *(const bf16x8*)(ap + (size_t)(0 * NKB + i + 2) * 512);
                a[nx][1] = *(const bf16x8*)(ap + (size_t)(1 * NKB + i + 2) * 512);
                b[nx][0] = *(const bf16x8*)(bp + (size_t)(0 * NKB + i + 2) * 512);
                b[nx][1] = *(const bf16x8*)(bp + (size_t)(1 * NKB + i + 2) * 512);
                b[nx][2] = *(const bf16x8*)(bp + (size_t)(2 * NKB + i + 2) * 512);
                b[nx][3] = *(const bf16x8*)(bp + (size_t)(3 * NKB + i + 2) * 512);
            }
            bf16x8 (&ac)[2] = a[i % 3];
            bf16x8 (&bc)[4] = b[i % 3];
            #pragma unroll
            for (int mi = 0; mi < 2; ++mi)
                #pragma unroll
                for (int ni = 0; ni < 4; ++ni)
                    acc[mi][ni] = __builtin_amdgcn_mfma_f32_16x16x32_bf16(ac[mi], bc[ni], acc[mi][ni], 0, 0, 0);
        }
        #pragma unroll
        for (int mi = 0; mi < 2; ++mi)
            #pragma unroll
            for (int ni = 0; ni < 4; ++ni)
                *(floatx4*)&red[wv * 2048 + ((mi * 4 + ni) * 64 + l) * 4] = acc[mi][ni];
        __syncthreads();
        if (tid < 256) {
            int cl = tid & 63, qo = tid >> 6;     // qo 0..3
            int ni = cl >> 4;
            int q0 = qo * 8;
            int li0 = ((q0 & 15) >> 2) * 16 + (cl & 15);
            int li1 = (((q0 + 4) & 15) >> 2) * 16 + (cl & 15);
            int base0 = (((q0 >> 4) * 4 + ni) * 64 + li0) * 4;
            int base1 = ((((q0 + 4) >> 4) * 4 + ni) * 64 + li1) * 4;
            floatx4 s0{0.f, 0.f, 0.f, 0.f}, s1{0.f, 0.f, 0.f, 0.f};
            #pragma unroll
            for (int ww = 0; ww < 8; ++ww) {
                s0 += *(const floatx4*)&red[ww * 2048 + base0];
                s1 += *(const floatx4*)&red[ww * 2048 + base1];
            }
            int col = nt * 64 + cl;
            if (col < NCOL) {
                int colc = col * 3 + c;
                if (colc < MC) {                  // Wb3 A-frag store (16B)
                    bf16x8 o;
                    #pragma unroll
                    for (int j = 0; j < 4; ++j) {
                        o[j]     = (short)f2bf(s0[j]);
                        o[4 + j] = (short)f2bf(s1[j]);
                    }
                    *(bf16x8*)(Wb3 + ((size_t)(colc >> 4) * 7 + mt) * 512
                                   + (size_t)((colc & 15) + qo * 16) * 8) = o;
                }
                if (c == 0 && mt == 0 && qo == 0 && col < 456) w1g[col] = s0[0];
                if (mt == 0 && col >= 456) {      // Jacc rows: [0]=q1 base, [1..10]=q2..11
                    float* jb = Jacc + (size_t)((col - 456) * 3 + c) * 11;
                    if (qo == 0) {
                        jb[0] = s0[1]; jb[1] = s0[2]; jb[2] = s0[3];
                        jb[3] = s1[0]; jb[4] = s1[1]; jb[5] = s1[2]; jb[6] = s1[3];
                    } else if (qo == 1) {
                        jb[7] = s0[0]; jb[8] = s0[1]; jb[9] = s0[2]; jb[10] = s0[3];
                    }
                }
            }
        }
    }
    grid.sync();
    // ================= phase 2: tail (640 virtual blocks) ====================
    {
        float (*Rs)[24][9]   = (float(*)[24][9])(smem);          // 3456 floats
        float (*Jl)[24][3]   = (float(*)[24][3])(smem + 3456);   // 1152
        float (*resR)[24][9] = (float(*)[24][9])(smem + 4608);   // 3456
        float (*rest_)[24][3]= (float(*)[24][3])(smem + 8064);   // 1152
        float* Msh           = smem + 9216;                      // 16*145 = 2320
        for (int v = bid; v < 640; v += 256) {
            int bt = v / 10, kp = v % 10;
            int b0 = bt * 16;
            int nmg = (kp == 9) ? 5 : 9;
            int mgbase = kp * 9;

            for (int i = t; i < 3456; i += 512)
                ((float*)Rs)[i] = Rsg[(size_t)b0 * 216 + i];
            for (int i = t; i < 1152; i += 512) {
                int bl = i / 72, jc = i % 72;
                const float* bp_ = Jacc + (size_t)jc * 11;
                const float* be  = beta + (size_t)(b0 + bl) * 10;
                float a = bp_[0];
                #pragma unroll
                for (int n = 0; n < 10; ++n) a += be[n] * bp_[1 + n];
                Jl[bl][jc / 3][jc % 3] = a;
            }
            __syncthreads();
            int wv = t >> 6, l = t & 63;
            if (wv == 0) {
                if (l < 48) {                     // one thread per (batch,row)
                    const int par[24] = {-1,0,0,0,1,2,3,4,5,6,7,8,9,9,9,12,13,14,16,17,18,19,20,21};
                    int bl = l / 3, rr = l % 3;
                    resR[bl][0][rr * 3 + 0] =  Rs[bl][0][rr * 3 + 0];
                    resR[bl][0][rr * 3 + 1] = -Rs[bl][0][rr * 3 + 1];
                    resR[bl][0][rr * 3 + 2] = -Rs[bl][0][rr * 3 + 2];
                    rest_[bl][0][rr] = Jl[bl][0][rr];
                    for (int i = 1; i < 24; ++i) {
                        int p = par[i];
                        float t0 = Jl[bl][i][0] - Jl[bl][p][0];
                        float t1 = Jl[bl][i][1] - Jl[bl][p][1];
                        float t2 = Jl[bl][i][2] - Jl[bl][p][2];
                        float a0 = resR[bl][p][rr * 3 + 0], a1 = resR[bl][p][rr * 3 + 1],
                              a2 = resR[bl][p][rr * 3 + 2];
                        resR[bl][i][rr * 3 + 0] = a0 * Rs[bl][i][0] + a1 * Rs[bl][i][3] + a2 * Rs[bl][i][6];
                        resR[bl][i][rr * 3 + 1] = a0 * Rs[bl][i][1] + a1 * Rs[bl][i][4] + a2 * Rs[bl][i][7];
                        resR[bl][i][rr * 3 + 2] = a0 * Rs[bl][i][2] + a1 * Rs[bl][i][5] + a2 * Rs[bl][i][8];
                        rest_[bl][i][rr] = a0 * t0 + a1 * t1 + a2 * t2 + rest_[bl][p][rr];
                    }
                }
            } else {
                const unsigned short* bp = xbf + (size_t)bt * 7 * 512 + l * 8;
                for (int mgl = wv - 1; mgl < nmg; mgl += 7) {
                    const unsigned short* ap = Wb3 + (size_t)(mgbase + mgl) * 7 * 512 + l * 8;
                    floatx4 acc{0.f, 0.f, 0.f, 0.f};
                    #pragma unroll
                    for (int kk = 0; kk < 7; ++kk)
                        acc = __builtin_amdgcn_mfma_f32_16x16x32_bf16(
                            *(const bf16x8*)(ap + (size_t)kk * 512),
                            *(const bf16x8*)(bp + (size_t)kk * 512), acc, 0, 0, 0);
                    int bl = l & 15, cc0 = mgl * 16 + (l >> 4) * 4;
                    #pragma unroll
                    for (int rr = 0; rr < 4; ++rr) Msh[bl * 145 + cc0 + rr] = acc[rr];
                }
            }
            __syncthreads();
            int nk = (kp == 9) ? 1 : 2;
            for (int i = t; i < 48 * nk; i += 512) {
                int kl = i / 48, r2 = i % 48;
                int bl = r2 / 3, c = r2 % 3;
                int b = b0 + bl, k = kp * 2 + kl;
                float s = trans[b * 3 + c];
                const float* mrow = Msh + bl * 145 + kl * 72;
                const float* w1k  = w1g + k * 24;
                #pragma unroll
                for (int j = 0; j < 24; ++j) {
                    float ta = rest_[bl][j][c]
                        - (resR[bl][j][c * 3 + 0] * Jl[bl][j][0]
                         + resR[bl][j][c * 3 + 1] * Jl[bl][j][1]
                         + resR[bl][j][c * 3 + 2] * Jl[bl][j][2]);
                    s += ta * w1k[j];
                    s += resR[bl][j][c * 3 + 0] * mrow[j * 3 + 0]
                       + resR[bl][j][c * 3 + 1] * mrow[j * 3 + 1]
                       + resR[bl][j][c * 3 + 2] * mrow[j * 3 + 2];
                }
                out[(size_t)b * 57 + k * 3 + c] = s;
            }
            __syncthreads();                      // protect smem reuse next round
        }
    }
}

extern "C" void kernel_launch(void* const* d_in, const int* in_sizes, int n_in,
                              void* d_out, int out_size, void* d_ws, size_t ws_size,
                              hipStream_t stream)
{
    const float* beta  = (const float*)d_in[0];
    const float* theta = (const float*)d_in[1];
    const float* trans = (const float*)d_in[2];
    const float* vt    = (const float*)d_in[3];
    const float* sdirs = (const float*)d_in[4];
    const float* Jreg  = (const float*)d_in[5];
    const float* pdirs = (const float*)d_in[6];
    const float* jreg  = (const float*)d_in[7];
    const float* wts   = (const float*)d_in[8];
    float* out = (float*)d_out;
    int B = in_sizes[0] / 10;   // 1024
    (void)B;

    // workspace layout (~19 MB), all 16B-aligned
    unsigned short* Af  = (unsigned short*)d_ws;                 // 42*216*512
    unsigned short* Bf  = Af + (size_t)42 * NKB * 512;           // 32*216*512
    unsigned short* Wb3 = Bf + (size_t)32 * NKB * 512;           // 88*7*512
    unsigned short* xbf = Wb3 + (size_t)88 * 7 * 512;            // 64*7*512
    float* Jacc = (float*)(xbf + (size_t)64 * 7 * 512);          // 792
    float* w1g  = Jacc + 792;                                    // 456
    float* Rsg  = w1g + 456;                                     // B*216

    void* args[] = {
        (void*)&vt, (void*)&sdirs, (void*)&pdirs, (void*)&Jreg, (void*)&jreg,
        (void*)&wts, (void*)&beta, (void*)&theta, (void*)&trans,
        (void*)&Af, (void*)&Bf, (void*)&Wb3, (void*)&xbf,
        (void*)&Jacc, (void*)&w1g, (void*)&Rsg, (void*)&out
    };
    hipLaunchCooperativeKernel((void*)mega, dim3(256), dim3(512), args, 0, stream);
}

// Round 11
// 124.875 us; speedup vs baseline: 1.8961x; 1.8961x over previous
//
#include <hip/hip_runtime.h>
#include <hip/hip_bf16.h>

// SMPL collapsed-form. R20 = R18 revert (best measured: 125.5us).
// R19's cooperative mega-kernel regressed to 236.8us (grid.sync convoying,
// 1 block/CU occupancy cap, 168/256 blocks idle in phase1, 1.87M LDS bank
// conflicts from shared-smem carving) — launch gaps (~14us) are cheaper than
// whole-grid barriers for heterogeneous phases. Ledger at R18: ~90us harness
// poison-fills (HBM-rooflined, untouchable), ~21us kernels (each near its own
// traffic floor), ~14us launch edges (removal path measured and rejected).
//  k0: LDS-staged coalesced frag build + partC (Rsg/xbf)
//  k1: 168 blocks x 8 waves, K split, LDS reduce -> Wb3/w1g/Jacc
//  k2: slim tail, 2 barriers, chain||MFMA split
// B=1024, V=6890, NB=10, NJ=24, NP=207, NK=19.
constexpr int Vn   = 6890;
constexpr int VC3  = 20670;   // V*3
constexpr int NKB  = 216;     // K blocks of 32 (K padded to 6912)
constexpr int QT   = 224;     // q rows: [ones, v_template, 10 shapedirs, 207 posedirs]
constexpr int NMG  = 14;      // QT/16 m-frag groups per c-plane
constexpr int NCOL = 480;     // 456 (k,j) cols + 24 Jreg cols
constexpr int MC   = 1368;    // 456*3
constexpr int KCH  = 27;      // k-blocks per wave in k1 (216/8)

using bf16x8  = __attribute__((ext_vector_type(8))) short;
using floatx4 = __attribute__((ext_vector_type(4))) float;

__device__ __forceinline__ unsigned short f2bf(float f) {
    unsigned int u = __float_as_uint(f);
    unsigned int r = (u + 0x7FFFu + ((u >> 16) & 1u)) >> 16;
    return (unsigned short)r;
}

// ---------- K0: build Af/Bf frags + partC (Rsg, xbf) ----------
__global__ __launch_bounds__(256) void k0_build(
    const float* __restrict__ vt, const float* __restrict__ sdirs,
    const float* __restrict__ pdirs, const float* __restrict__ Jreg,
    const float* __restrict__ jreg, const float* __restrict__ wts,
    const float* __restrict__ beta, const float* __restrict__ theta,
    unsigned short* __restrict__ Af, unsigned short* __restrict__ Bf,
    float* __restrict__ Rsg, unsigned short* __restrict__ xbf)
{
    __shared__ float smem[16 * 385];          // 24.6 KB, carved per branch
    int bx = blockIdx.x, t = threadIdx.x;
    if (bx < 756) {                           // ---- part A: 14 mg x 54 u-chunks
        int mg = bx / 54, ub = bx % 54;
        int fbase = ub * 384;                 // first float of this chunk in each row
        // stage: 16 rows x 384 consecutive floats, coalesced; rows padded to 385
        for (int i = t; i < 16 * 384; i += 256) {
            int qr = i / 384, off = i % 384;
            int q = mg * 16 + qr;
            int gidx = fbase + off;
            float v = 0.f;
            if (q == 0) v = (gidx < VC3) ? 1.f : 0.f;
            else {
                const float* src = nullptr;
                if (q == 1) src = vt;
                else if (q < 12)  src = sdirs + (size_t)(q - 2) * VC3;
                else if (q < 219) src = pdirs + (size_t)(q - 12) * VC3;
                if (src && gidx < VC3) v = src[gidx];
            }
            smem[qr * 385 + off] = v;
        }
        __syncthreads();
        // frag build: wave writes one contiguous 1KB frag per c
        int ql = t & 15, uul = t >> 4;
        int uu = ub * 16 + uul;
        int kb = uu >> 2, quad = uu & 3;
        size_t foff = (size_t)(ql + quad * 16) * 8;
        const float* lrow = smem + ql * 385 + uul * 24;
        #pragma unroll
        for (int c = 0; c < 3; ++c) {
            bf16x8 o;
            #pragma unroll
            for (int j = 0; j < 8; ++j) o[j] = (short)f2bf(lrow[3 * j + c]);
            *(bf16x8*)(Af + ((size_t)(c * NMG + mg) * NKB + kb) * 512 + foff) = o;
        }
        return;
    }
    bx -= 756;
    if (bx < 108) {                           // ---- part B (108 blocks, 64 v each)
        int v0 = bx * 64;
        float* js  = smem;                    // 64*19
        float* wsh = smem + 1216;             // 64*24
        float* Jsh = smem + 2752;             // 64*24
        for (int i = t; i < 64 * 19; i += 256)
            js[i] = (v0 * 19 + i < Vn * 19) ? jreg[v0 * 19 + i] : 0.f;
        for (int i = t; i < 64 * 24; i += 256) {
            wsh[i] = (v0 * 24 + i < Vn * 24) ? wts[v0 * 24 + i] : 0.f;
            Jsh[i] = (v0 * 24 + i < Vn * 24) ? Jreg[v0 * 24 + i] : 0.f;
        }
        __syncthreads();
        for (int s = t; s < 4096; s += 256) { // 512 cols x 8 v-groups
            int clow = s & 15, w = s >> 4;
            int vg = w & 7, chigh = w >> 3;
            int col = chigh * 16 + clow;
            int kb = (v0 >> 5) + (vg >> 2);
            bf16x8 o;
            #pragma unroll
            for (int j = 0; j < 8; ++j) {
                int vl = vg * 8 + j;
                float val = 0.f;
                if (col < 456)      val = js[vl * 19 + col / 24] * wsh[vl * 24 + col % 24];
                else if (col < 480) val = Jsh[vl * 24 + (col - 456)];
                o[j] = (short)f2bf(val);
            }
            *(bf16x8*)(Bf + ((size_t)chigh * NKB + kb) * 512
                          + (size_t)(clow + (vg & 3) * 16) * 8) = o;
        }
        return;
    }
    bx -= 108;
    {                                         // ---- part C (64 blocks, 16 batches each)
        float (*Rc)[24][9] = (float(*)[24][9])smem;
        int b0 = bx * 16;
        for (int i = t; i < 384; i += 256) {  // rodrigues
            int bl = i / 24, j = i % 24;
            float t0 = theta[(size_t)(b0 + bl) * 72 + j * 3 + 0];
            float t1 = theta[(size_t)(b0 + bl) * 72 + j * 3 + 1];
            float t2 = theta[(size_t)(b0 + bl) * 72 + j * 3 + 2];
            float e0 = t0 + 1e-8f, e1 = t1 + 1e-8f, e2 = t2 + 1e-8f;
            float angle = sqrtf(e0 * e0 + e1 * e1 + e2 * e2);
            float half = 0.5f * angle;
            float sh = sinf(half), ch = cosf(half);
            float s = sh / angle;
            float qx = t0 * s, qy = t1 * s, qz = t2 * s;
            float qn = sqrtf(ch * ch + qx * qx + qy * qy + qz * qz);
            float w = ch / qn, x = qx / qn, y = qy / qn, z = qz / qn;
            float r0 = 1.f - 2.f * (y * y + z * z);
            float r1 = 2.f * (x * y - w * z);
            float r2 = 2.f * (x * z + w * y);
            float r3 = 2.f * (x * y + w * z);
            float r4 = 1.f - 2.f * (x * x + z * z);
            float r5 = 2.f * (y * z - w * x);
            float r6 = 2.f * (x * z - w * y);
            float r7 = 2.f * (y * z + w * x);
            float r8 = 1.f - 2.f * (x * x + y * y);
            Rc[bl][j][0] = r0; Rc[bl][j][1] = r1; Rc[bl][j][2] = r2;
            Rc[bl][j][3] = r3; Rc[bl][j][4] = r4; Rc[bl][j][5] = r5;
            Rc[bl][j][6] = r6; Rc[bl][j][7] = r7; Rc[bl][j][8] = r8;
            float* rg = Rsg + (size_t)(b0 + bl) * 216 + j * 9;
            rg[0] = r0; rg[1] = r1; rg[2] = r2;
            rg[3] = r3; rg[4] = r4; rg[5] = r5;
            rg[6] = r6; rg[7] = r7; rg[8] = r8;
        }
        __syncthreads();
        for (int i = t; i < 16 * QT; i += 256) {   // x frags
            int q = i >> 4, bl = i & 15;
            int b = b0 + bl;
            float xv = 0.f;
            if (q == 1) xv = 1.f;
            else if (q >= 2 && q < 12) xv = beta[(size_t)b * 10 + (q - 2)];
            else if (q >= 12 && q < 219) {
                int p = q - 12;
                int jj = 1 + p / 9, e = p % 9;
                float rr = Rc[bl][jj][e];
                if (e == 0 || e == 4 || e == 8) rr -= 1.f;
                xv = rr;
            }
            xbf[((size_t)(b >> 4) * 7 + (q >> 5)) * 512
                + (size_t)((b & 15) + ((q >> 3) & 3) * 16) * 8 + (q & 7)] = f2bf(xv);
        }
    }
}

// ---------- K1: 32x64 tile per block, 8 waves split K, LDS reduce -> Wb3/w1g/Jacc ----------
__device__ __forceinline__ void k1_load(bf16x8 (&a)[2], bf16x8 (&b)[4],
    const unsigned short* __restrict__ ap, const unsigned short* __restrict__ bp, int i)
{
    a[0] = *(const bf16x8*)(ap + (size_t)(0 * NKB + i) * 512);
    a[1] = *(const bf16x8*)(ap + (size_t)(1 * NKB + i) * 512);
    b[0] = *(const bf16x8*)(bp + (size_t)(0 * NKB + i) * 512);
    b[1] = *(const bf16x8*)(bp + (size_t)(1 * NKB + i) * 512);
    b[2] = *(const bf16x8*)(bp + (size_t)(2 * NKB + i) * 512);
    b[3] = *(const bf16x8*)(bp + (size_t)(3 * NKB + i) * 512);
}

__global__ __launch_bounds__(512) void k1_mfma(
    const unsigned short* __restrict__ Af, const unsigned short* __restrict__ Bf,
    unsigned short* __restrict__ Wb3, float* __restrict__ w1g,
    float* __restrict__ Jacc)
{
    __shared__ float red[8 * 2048];           // 64 KB
    int tid = threadIdx.x;
    int wv = tid >> 6, l = tid & 63;
    int r = blockIdx.x;
    int c = r / 56; r %= 56;
    int mt = r >> 3, nt = r & 7;
    int kb0 = wv * KCH;

    const unsigned short* ap = Af + ((size_t)(c * NMG + mt * 2) * NKB + kb0) * 512 + l * 8;
    const unsigned short* bp = Bf + ((size_t)(nt * 4) * NKB + kb0) * 512 + l * 8;

    floatx4 acc[2][4];
    #pragma unroll
    for (int mi = 0; mi < 2; ++mi)
        #pragma unroll
        for (int ni = 0; ni < 4; ++ni) acc[mi][ni] = floatx4{0.f, 0.f, 0.f, 0.f};

    bf16x8 a[3][2], b[3][4];
    k1_load(a[0], b[0], ap, bp, 0);
    k1_load(a[1], b[1], ap, bp, 1);
    #pragma unroll
    for (int i = 0; i < KCH; ++i) {
        if (i + 2 < KCH) k1_load(a[(i + 2) % 3], b[(i + 2) % 3], ap, bp, i + 2);
        bf16x8 (&ac)[2] = a[i % 3];
        bf16x8 (&bc)[4] = b[i % 3];
        #pragma unroll
        for (int mi = 0; mi < 2; ++mi)
            #pragma unroll
            for (int ni = 0; ni < 4; ++ni)
                acc[mi][ni] = __builtin_amdgcn_mfma_f32_16x16x32_bf16(ac[mi], bc[ni], acc[mi][ni], 0, 0, 0);
    }
    #pragma unroll
    for (int mi = 0; mi < 2; ++mi)
        #pragma unroll
        for (int ni = 0; ni < 4; ++ni)
            *(floatx4*)&red[wv * 2048 + ((mi * 4 + ni) * 64 + l) * 4] = acc[mi][ni];
    __syncthreads();
    if (tid < 256) {
        int cl = tid & 63, qo = tid >> 6;     // qo 0..3
        int ni = cl >> 4;
        int q0 = qo * 8;
        int li0 = ((q0 & 15) >> 2) * 16 + (cl & 15);
        int li1 = (((q0 + 4) & 15) >> 2) * 16 + (cl & 15);
        int base0 = (((q0 >> 4) * 4 + ni) * 64 + li0) * 4;
        int base1 = ((((q0 + 4) >> 4) * 4 + ni) * 64 + li1) * 4;
        floatx4 s0{0.f, 0.f, 0.f, 0.f}, s1{0.f, 0.f, 0.f, 0.f};
        #pragma unroll
        for (int ww = 0; ww < 8; ++ww) {
            s0 += *(const floatx4*)&red[ww * 2048 + base0];
            s1 += *(const floatx4*)&red[ww * 2048 + base1];
        }
        int col = nt * 64 + cl;
        if (col < NCOL) {
            int colc = col * 3 + c;
            if (colc < MC) {                  // Wb3 A-frag store (16B)
                bf16x8 o;
                #pragma unroll
                for (int j = 0; j < 4; ++j) {
                    o[j]     = (short)f2bf(s0[j]);
                    o[4 + j] = (short)f2bf(s1[j]);
                }
                *(bf16x8*)(Wb3 + ((size_t)(colc >> 4) * 7 + mt) * 512
                               + (size_t)((colc & 15) + qo * 16) * 8) = o;
            }
            if (c == 0 && mt == 0 && qo == 0 && col < 456) w1g[col] = s0[0];
            if (mt == 0 && col >= 456) {      // Jacc rows: [0]=q1 base, [1..10]=q2..11
                float* jb = Jacc + (size_t)((col - 456) * 3 + c) * 11;
                if (qo == 0) {
                    jb[0] = s0[1]; jb[1] = s0[2]; jb[2] = s0[3];
                    jb[3] = s1[0]; jb[4] = s1[1]; jb[5] = s1[2]; jb[6] = s1[3];
                } else if (qo == 1) {
                    jb[7] = s0[0]; jb[8] = s0[1]; jb[9] = s0[2]; jb[10] = s0[3];
                }
            }
        }
    }
}

// ---------- K2: slim tail, 2 barriers. Block = (bt, kp): 16 batches, joints {2kp,2kp+1} ----------
__global__ __launch_bounds__(512) void k2_tail(
    const unsigned short* __restrict__ Wb3, const unsigned short* __restrict__ xbf,
    const float* __restrict__ Rsg, const float* __restrict__ Jacc,
    const float* __restrict__ w1g, const float* __restrict__ beta,
    const float* __restrict__ trans, float* __restrict__ out)
{
    __shared__ float Rs[16][24][9];           // 13,824 B
    __shared__ float Jl[16][24][3];           //  4,608
    __shared__ float resR[16][24][9];         // 13,824
    __shared__ float rest_[16][24][3];        //  4,608
    __shared__ float Msh[16][145];            //  9,280  -> ~46.1 KB, 3 blocks/CU
    int t = threadIdx.x;
    int bt = blockIdx.x / 10, kp = blockIdx.x % 10;
    int b0 = bt * 16;
    int nmg = (kp == 9) ? 5 : 9;
    int mgbase = kp * 9;

    // ---- stage: Rs coalesced; Jl with direct beta reads (no bet LDS, no extra barrier)
    for (int i = t; i < 3456; i += 512)
        ((float*)Rs)[i] = Rsg[(size_t)b0 * 216 + i];
    for (int i = t; i < 1152; i += 512) {
        int bl = i / 72, jc = i % 72;
        const float* bp_ = Jacc + (size_t)jc * 11;
        const float* be  = beta + (size_t)(b0 + bl) * 10;
        float a = bp_[0];
        #pragma unroll
        for (int n = 0; n < 10; ++n) a += be[n] * bp_[1 + n];
        Jl[bl][jc / 3][jc % 3] = a;
    }
    __syncthreads();
    // ---- wave0: kinematic chain; waves 1..7: MFMA tiles
    int wv = t >> 6, l = t & 63;
    if (wv == 0) {
        if (l < 48) {                         // one thread per (batch,row)
            const int par[24] = {-1,0,0,0,1,2,3,4,5,6,7,8,9,9,9,12,13,14,16,17,18,19,20,21};
            int bl = l / 3, rr = l % 3;
            resR[bl][0][rr * 3 + 0] =  Rs[bl][0][rr * 3 + 0];
            resR[bl][0][rr * 3 + 1] = -Rs[bl][0][rr * 3 + 1];
            resR[bl][0][rr * 3 + 2] = -Rs[bl][0][rr * 3 + 2];
            rest_[bl][0][rr] = Jl[bl][0][rr];
            for (int i = 1; i < 24; ++i) {
                int p = par[i];
                float t0 = Jl[bl][i][0] - Jl[bl][p][0];
                float t1 = Jl[bl][i][1] - Jl[bl][p][1];
                float t2 = Jl[bl][i][2] - Jl[bl][p][2];
                float a0 = resR[bl][p][rr * 3 + 0], a1 = resR[bl][p][rr * 3 + 1],
                      a2 = resR[bl][p][rr * 3 + 2];
                resR[bl][i][rr * 3 + 0] = a0 * Rs[bl][i][0] + a1 * Rs[bl][i][3] + a2 * Rs[bl][i][6];
                resR[bl][i][rr * 3 + 1] = a0 * Rs[bl][i][1] + a1 * Rs[bl][i][4] + a2 * Rs[bl][i][7];
                resR[bl][i][rr * 3 + 2] = a0 * Rs[bl][i][2] + a1 * Rs[bl][i][5] + a2 * Rs[bl][i][8];
                rest_[bl][i][rr] = a0 * t0 + a1 * t1 + a2 * t2 + rest_[bl][p][rr];
            }
        }
    } else {
        const unsigned short* bp = xbf + (size_t)bt * 7 * 512 + l * 8;
        for (int mgl = wv - 1; mgl < nmg; mgl += 7) {
            const unsigned short* ap = Wb3 + (size_t)(mgbase + mgl) * 7 * 512 + l * 8;
            floatx4 acc{0.f, 0.f, 0.f, 0.f};
            #pragma unroll
            for (int kk = 0; kk < 7; ++kk)
                acc = __builtin_amdgcn_mfma_f32_16x16x32_bf16(
                    *(const bf16x8*)(ap + (size_t)kk * 512),
                    *(const bf16x8*)(bp + (size_t)kk * 512), acc, 0, 0, 0);
            int bl = l & 15, cc0 = mgl * 16 + (l >> 4) * 4;
            #pragma unroll
            for (int rr = 0; rr < 4; ++rr) Msh[bl][cc0 + rr] = acc[rr];
        }
    }
    __syncthreads();
    // ---- out = trans + tA.w1 + RA.M (tA inline; w1 direct from global; pure store)
    int nk = (kp == 9) ? 1 : 2;
    for (int i = t; i < 48 * nk; i += 512) {
        int kl = i / 48, r2 = i % 48;
        int bl = r2 / 3, c = r2 % 3;
        int b = b0 + bl, k = kp * 2 + kl;
        float s = trans[b * 3 + c];
        const float* mrow = Msh[bl] + kl * 72;
        const float* w1k  = w1g + k * 24;
        #pragma unroll
        for (int j = 0; j < 24; ++j) {
            float ta = rest_[bl][j][c]
                - (resR[bl][j][c * 3 + 0] * Jl[bl][j][0]
                 + resR[bl][j][c * 3 + 1] * Jl[bl][j][1]
                 + resR[bl][j][c * 3 + 2] * Jl[bl][j][2]);
            s += ta * w1k[j];
            s += resR[bl][j][c * 3 + 0] * mrow[j * 3 + 0]
               + resR[bl][j][c * 3 + 1] * mrow[j * 3 + 1]
               + resR[bl][j][c * 3 + 2] * mrow[j * 3 + 2];
        }
        out[(size_t)b * 57 + k * 3 + c] = s;
    }
}

extern "C" void kernel_launch(void* const* d_in, const int* in_sizes, int n_in,
                              void* d_out, int out_size, void* d_ws, size_t ws_size,
                              hipStream_t stream)
{
    const float* beta  = (const float*)d_in[0];
    const float* theta = (const float*)d_in[1];
    const float* trans = (const float*)d_in[2];
    const float* vt    = (const float*)d_in[3];
    const float* sdirs = (const float*)d_in[4];
    const float* Jreg  = (const float*)d_in[5];
    const float* pdirs = (const float*)d_in[6];
    const float* jreg  = (const float*)d_in[7];
    const float* wts   = (const float*)d_in[8];
    float* out = (float*)d_out;
    int B = in_sizes[0] / 10;   // 1024

    // workspace layout (~19 MB), all 16B-aligned
    unsigned short* Af  = (unsigned short*)d_ws;                 // 42*216*512
    unsigned short* Bf  = Af + (size_t)42 * NKB * 512;           // 32*216*512
    unsigned short* Wb3 = Bf + (size_t)32 * NKB * 512;           // 88*7*512
    unsigned short* xbf = Wb3 + (size_t)88 * 7 * 512;            // 64*7*512
    float* Jacc = (float*)(xbf + (size_t)64 * 7 * 512);          // 792
    float* w1g  = Jacc + 792;                                    // 456
    float* Rsg  = w1g + 456;                                     // B*216

    k0_build<<<dim3(756 + 108 + 64), 256, 0, stream>>>(
        vt, sdirs, pdirs, Jreg, jreg, wts, beta, theta, Af, Bf, Rsg, xbf);
    k1_mfma<<<dim3(168), 512, 0, stream>>>(Af, Bf, Wb3, w1g, Jacc);
    k2_tail<<<dim3((B / 16) * 10), 512, 0, stream>>>(
        Wb3, xbf, Rsg, Jacc, w1g, beta, trans, out);
}